// Round 11
// baseline (188.441 us; speedup 1.0000x reference)
//
#include <hip/hip_runtime.h>
#include <hip/hip_bf16.h>
#include <string.h>

// DeformableConv1D: B=4, Cin=256, Cout=256, L=8192, K=7, stride=1, pad=3, dil=1
// out[b,o,l] = sum_{i,kt} w[o,i,kt] * interp(b, l, i, kt) + bias[o]
// loc[b,l,kt] = l + kt + (offset_conv(x)[b,l,kt] + offset_b[kt])
// interp = wa*x[b,i,x0c] + wb*x[b,i,x1c]
//
// Round 11:
//  - loc_partial: 2 l/thread, grid 1024 (4 blocks/CU) -> 2x TLP for the
//    overlapping-window loads.
//  - main: 2-deep gather pipeline (two register sets; each CVT >= 2 MFMA
//    K-steps after its loads issue); packed bf16 convert via
//    __float22bfloat162_rn + memcpy (hoping for v_cvt_pk_bf16_f32).

#define B_    4
#define CIN   256
#define COUT  256
#define LEN   8192
#define KK    7
#define NTOT  (B_ * LEN)          // 32768 = 1<<15
#define QTOT  (CIN * KK)          // 1792
#define LPITCH 232                // LDS row pitch (elems); 464 B

typedef short s16x8 __attribute__((ext_vector_type(8)));
typedef int   s32x4 __attribute__((ext_vector_type(4)));
typedef float f32x4 __attribute__((ext_vector_type(4)));

static __device__ __forceinline__ unsigned f2bf(float f) {
  union { float f; unsigned u; } u; u.f = f;
  unsigned r = u.u + 0x7FFF + ((u.u >> 16) & 1);   // RNE (finite inputs)
  return r >> 16;
}

static __device__ __forceinline__ int pack_bf16(float a, float d) {
  __hip_bfloat162 h = __float22bfloat162_rn(make_float2(a, d));
  int r;
  __builtin_memcpy(&r, &h, 4);
  return r;
}

// ---------------------------------------------------------------------------
// Kernel 1: offset-conv partials. Grid 1024: cg = bid>>8 (4 ch-groups of 64),
// 128 l per block. Wave w: 16 channels; thread: 2 l (lane + 64r).
// OW loads uniform (s_load). LDS reduce over waves. Partial[(cg*7+k)][n].
// ---------------------------------------------------------------------------
__global__ __launch_bounds__(256) void loc_partial(
    const float* __restrict__ X, const float* __restrict__ OW,
    float* __restrict__ Partial) {
  __shared__ float red[4][128][KK];            // 14336 B

  const int t    = threadIdx.x;
  const int lane = t & 63;
  const int wu   = __builtin_amdgcn_readfirstlane(t >> 6);
  const int cg   = blockIdx.x >> 8;            // 0..3
  const int nb   = (blockIdx.x & 255) << 7;    // 128 n per block
  const int b    = nb >> 13;
  const int l0   = nb & (LEN - 1);

  float acc[KK][2];
#pragma unroll
  for (int k = 0; k < KK; ++k)
#pragma unroll
    for (int r = 0; r < 2; ++r) acc[k][r] = 0.0f;

#pragma unroll 2
  for (int ii = 0; ii < 16; ++ii) {
    const int i = cg * 64 + wu * 16 + ii;      // uniform
    float owv[49];
#pragma unroll
    for (int k = 0; k < KK; ++k)
#pragma unroll
      for (int j = 0; j < KK; ++j)
        owv[k * 7 + j] = OW[(k * CIN + i) * KK + j];   // uniform -> s_load

    const float* xr = X + ((size_t)(b * CIN + i) << 13);
#pragma unroll
    for (int r = 0; r < 2; ++r) {
      const int lr = l0 + lane + 64 * r;
      float xv[KK];
#pragma unroll
      for (int j = 0; j < KK; ++j) {
        int pos = lr + j - 3;
        xv[j] = ((unsigned)pos < LEN) ? xr[pos] : 0.0f;
      }
#pragma unroll
      for (int k = 0; k < KK; ++k)
#pragma unroll
        for (int j = 0; j < KK; ++j)
          acc[k][r] += xv[j] * owv[k * 7 + j];
    }
  }

#pragma unroll
  for (int k = 0; k < KK; ++k)
#pragma unroll
    for (int r = 0; r < 2; ++r) red[wu][lane + 64 * r][k] = acc[k][r];
  __syncthreads();

  if (t < 128) {
#pragma unroll
    for (int k = 0; k < KK; ++k) {
      float s = red[0][t][k] + red[1][t][k] + red[2][t][k] + red[3][t][k];
      Partial[((size_t)(cg * 7 + k) << 15) + nb + t] = s;   // coalesced
    }
  }
}

// ---------------------------------------------------------------------------
// Kernel 2: Loc[k][n] = (l+k) + OB[k] + sum_cg Partial[cg*7+k][n]
// ---------------------------------------------------------------------------
__global__ __launch_bounds__(256) void loc_reduce(
    const float* __restrict__ Partial, const float* __restrict__ OB,
    float* __restrict__ Loc) {
  int n = blockIdx.x * 256 + threadIdx.x;      // grid 128 -> 32768
  int l = n & (LEN - 1);
#pragma unroll
  for (int k = 0; k < KK; ++k) {
    float s = (float)(l + k) + OB[k];
#pragma unroll
    for (int cg = 0; cg < 4; ++cg)
      s += Partial[((size_t)(cg * 7 + k) << 15) + n];
    Loc[((size_t)k << 15) + n] = s;
  }
}

// ---------------------------------------------------------------------------
// Kernel 3: weights -> bf16 A-fragments via LDS (coalesced both sides).
// frag f = (ot*8+c)*7 + s, elem lane*8+j = W[ot*16+(lane&15)]
//   [(c*32+(lane>>4)*8+j)*7 + s].  Grid 128.
// ---------------------------------------------------------------------------
__global__ __launch_bounds__(256) void wt_build(
    const float* __restrict__ W, unsigned short* __restrict__ Wf) {
  __shared__ float Wl[16 * 32 * KK];           // 14336 B
  const int t  = threadIdx.x;
  const int ot = blockIdx.x >> 3;
  const int c  = blockIdx.x & 7;

  for (int e = t; e < 16 * 32 * KK; e += 256) {
    int o = e / 224;
    int r = e - o * 224;
    Wl[e] = W[(size_t)(ot * 16 + o) * QTOT + c * 224 + r];
  }
  __syncthreads();

  const int lane = t & 63;
  const int sg   = t >> 6;
  const int ol   = lane & 15;
  const int ig   = lane >> 4;
  for (int s = sg; s < KK; s += 4) {
    s16x8 v;
#pragma unroll
    for (int j = 0; j < 8; ++j)
      v[j] = (short)f2bf(Wl[ol * 224 + (ig * 8 + j) * KK + s]);
    int f = (ot * 8 + c) * KK + s;
    *(s16x8*)(Wf + ((size_t)f << 9) + (lane << 3)) = v;
  }
}

// ---------------------------------------------------------------------------
// Kernel 4: main MFMA GEMM. Block = 512 threads (8 waves), 256 o x 64 n,
// grid 512. 2-deep gather pipeline: two register sets (rs 0/1); every CVT
// consumes loads issued >= 2 MFMA K-steps earlier. af frags register-loaded
// before gathers (sched_barrier pins order). Double-buffered Il.
// ---------------------------------------------------------------------------
__global__ __launch_bounds__(512, 4) void main_kernel(
    const float* __restrict__ X, const unsigned short* __restrict__ Wf,
    const float* __restrict__ Bias, const float* __restrict__ Loc,
    float* __restrict__ Out) {
  __shared__ unsigned short Il[2][64][LPITCH];   // 59392 B

  const int t    = threadIdx.x;
  const int lane = t & 63;
  const int w    = t >> 6;                     // 0..7
  const int n0   = blockIdx.x << 6;            // grid 512
  const int b    = n0 >> 13;
  const float* Xb = X + ((size_t)b << 21);

  const bool stager = (t < 448);
  const int nl = t & 63;
  const int kt = t >> 6;                       // 0..6 when stager

  float c0 = 0.f, c1 = 0.f;
  const float* xp = Xb;
  if (stager) {
    float locv = Loc[((size_t)kt << 15) + n0 + nl];
    int x0  = (int)floorf(locv);
    int x0c = min(max(x0, 0), LEN - 1);
    int x1c = min(max(x0 + 1, 0), LEN - 1);
    float wa = (float)x1c - locv;
    float wb = locv - (float)x0c;
    bool hi = (x0 >= LEN - 1);
    bool lo = (x0 < 0);
    c0 = (hi ? 0.f : wa) + (lo ? wb : 0.f);   // coeff of x[p0]
    c1 = (hi ? wa : 0.f) + (lo ? 0.f : wb);   // coeff of x[p0+1]
    xp = Xb + min(max(x0, 0), LEN - 2);
  }

  f32x4 acc[2][4];
#pragma unroll
  for (int a = 0; a < 2; ++a)
#pragma unroll
    for (int cc = 0; cc < 4; ++cc) acc[a][cc] = (f32x4){0.f, 0.f, 0.f, 0.f};

  const int mrow = lane & 15;
  const int quad = lane >> 4;

  float f0[2][8], f1[2][8];                    // two gather register sets

#define GATHER_Q(chunk, q, rs)                                    \
  if (stager) {                                                   \
    _Pragma("unroll")                                             \
    for (int m = 0; m < 8; ++m) {                                 \
      const float* xr = xp + ((size_t)((chunk) * 32 + (q) * 8 + m) << 13); \
      f0[rs][m] = xr[0];                                          \
      f1[rs][m] = xr[1];                                          \
    }                                                             \
  }

#define CVT_Q(dst, q, rs)                                         \
  if (stager) {                                                   \
    s32x4 vv;                                                     \
    _Pragma("unroll")                                             \
    for (int m = 0; m < 4; ++m) {                                 \
      float a = c0 * f0[rs][2 * m]     + c1 * f1[rs][2 * m];      \
      float d = c0 * f0[rs][2 * m + 1] + c1 * f1[rs][2 * m + 1];  \
      vv[m] = pack_bf16(a, d);                                    \
    }                                                             \
    *(s32x4*)((dst) + nl * LPITCH + kt * 32 + (q) * 8) = vv;      \
  }

#define AFL(ttv, sv)                                              \
  (*(const s16x8*)(Wf + ((size_t)(((w * 2 + (ttv)) * 8 + c) * KK + (sv)) << 9) + (lane << 3)))

#define MSTEP(sv, a0, a1) {                                                        \
    const s16x8 b0 = *(const s16x8*)(Icur + (mrow)      * LPITCH + (sv) * 32 + quad * 8); \
    const s16x8 b1 = *(const s16x8*)(Icur + (16 + mrow) * LPITCH + (sv) * 32 + quad * 8); \
    acc[0][0] = __builtin_amdgcn_mfma_f32_16x16x32_bf16(a0, b0, acc[0][0], 0, 0, 0); \
    acc[1][0] = __builtin_amdgcn_mfma_f32_16x16x32_bf16(a1, b0, acc[1][0], 0, 0, 0); \
    acc[0][1] = __builtin_amdgcn_mfma_f32_16x16x32_bf16(a0, b1, acc[0][1], 0, 0, 0); \
    acc[1][1] = __builtin_amdgcn_mfma_f32_16x16x32_bf16(a1, b1, acc[1][1], 0, 0, 0); \
    const s16x8 b2 = *(const s16x8*)(Icur + (32 + mrow) * LPITCH + (sv) * 32 + quad * 8); \
    const s16x8 b3 = *(const s16x8*)(Icur + (48 + mrow) * LPITCH + (sv) * 32 + quad * 8); \
    acc[0][2] = __builtin_amdgcn_mfma_f32_16x16x32_bf16(a0, b2, acc[0][2], 0, 0, 0); \
    acc[1][2] = __builtin_amdgcn_mfma_f32_16x16x32_bf16(a1, b2, acc[1][2], 0, 0, 0); \
    acc[0][3] = __builtin_amdgcn_mfma_f32_16x16x32_bf16(a0, b3, acc[0][3], 0, 0, 0); \
    acc[1][3] = __builtin_amdgcn_mfma_f32_16x16x32_bf16(a1, b3, acc[1][3], 0, 0, 0); \
  }

  // prologue: stage chunk 0 into Il[0] (single register set, serial)
  {
    unsigned short* I0 = &Il[0][0][0];
    GATHER_Q(0, 0, 0) CVT_Q(I0, 0, 0)
    GATHER_Q(0, 1, 0) CVT_Q(I0, 1, 0)
    GATHER_Q(0, 2, 0) CVT_Q(I0, 2, 0)
    GATHER_Q(0, 3, 0) CVT_Q(I0, 3, 0)
  }
  __syncthreads();

  for (int c = 0; c < 8; ++c) {
    const int cur = c & 1;
    const unsigned short* Icur = &Il[cur][0][0];
    unsigned short*       Inxt = &Il[cur ^ 1][0][0];

    // af fragments s=0..3 FIRST (before any gather this chunk)
    s16x8 afA[2][4];
#pragma unroll
    for (int tt = 0; tt < 2; ++tt)
#pragma unroll
      for (int s = 0; s < 4; ++s) afA[tt][s] = AFL(tt, s);
    __builtin_amdgcn_sched_barrier(0);

    if (c < 7) { GATHER_Q(c + 1, 0, 0) }
    MSTEP(0, afA[0][0], afA[1][0])
    if (c < 7) { GATHER_Q(c + 1, 1, 1) }
    MSTEP(1, afA[0][1], afA[1][1])
    if (c < 7) { CVT_Q(Inxt, 0, 0) }          // Q0 issued 2 MSTEPs ago

    s16x8 afB[2][3];
#pragma unroll
    for (int tt = 0; tt < 2; ++tt)
#pragma unroll
      for (int s = 0; s < 3; ++s) afB[tt][s] = AFL(tt, 4 + s);
    __builtin_amdgcn_sched_barrier(0);

    MSTEP(2, afA[0][2], afA[1][2])
    if (c < 7) { GATHER_Q(c + 1, 2, 0) }
    MSTEP(3, afA[0][3], afA[1][3])
    if (c < 7) { CVT_Q(Inxt, 1, 1) }          // Q1 issued 3 MSTEPs ago
    MSTEP(4, afB[0][0], afB[1][0])
    if (c < 7) { GATHER_Q(c + 1, 3, 1) }
    MSTEP(5, afB[0][1], afB[1][1])
    if (c < 7) { CVT_Q(Inxt, 2, 0) }          // Q2 issued 2 MSTEPs ago
    MSTEP(6, afB[0][2], afB[1][2])
    if (c < 7) {
      CVT_Q(Inxt, 3, 1)                       // Q3 issued 2 MSTEPs ago
      __syncthreads();
    }
  }
#undef GATHER_Q
#undef CVT_Q
#undef AFL
#undef MSTEP

  // epilogue: D row m = quad*4+r (o), col = mrow (l)
  const int lbase = (n0 & (LEN - 1)) + mrow;
#pragma unroll
  for (int tt = 0; tt < 2; ++tt) {
    const int obase = (w * 2 + tt) * 16 + quad * 4;
#pragma unroll
    for (int r = 0; r < 4; ++r) {
      const int o = obase + r;
      const float bv = Bias[o];
      float* orow = Out + (((size_t)(b * COUT + o)) << 13) + lbase;
#pragma unroll
      for (int nt = 0; nt < 4; ++nt)
        orow[nt * 16] = acc[tt][nt][r] + bv;
    }
  }
}

extern "C" void kernel_launch(void* const* d_in, const int* in_sizes, int n_in,
                              void* d_out, int out_size, void* d_ws, size_t ws_size,
                              hipStream_t stream) {
  const float* X    = (const float*)d_in[0];   // (4,256,8192)
  const float* W    = (const float*)d_in[1];   // (256,256,7)
  const float* Bias = (const float*)d_in[2];   // (256,)
  const float* OW   = (const float*)d_in[3];   // (7,256,7)
  const float* OB   = (const float*)d_in[4];   // (7,)
  float* Out = (float*)d_out;                  // (4,256,8192)

  // ws: Loc (0.92 MB) | Wf (0.92 MB) | Partial (3.5 MB)  = 5.4 MB
  float* Loc = (float*)d_ws;
  unsigned short* Wf = (unsigned short*)(Loc + (size_t)NTOT * KK);
  float* Partial = (float*)(Wf + (size_t)COUT * QTOT);

  loc_partial<<<4 * 256, 256, 0, stream>>>(X, OW, Partial);
  loc_reduce<<<NTOT / 256, 256, 0, stream>>>(Partial, OB, Loc);
  wt_build<<<128, 256, 0, stream>>>(W, Wf);
  main_kernel<<<NTOT / 64, 512, 0, stream>>>(X, Wf, Bias, Loc, Out);
}